// Round 5
// baseline (308.899 us; speedup 1.0000x reference)
//
#include <hip/hip_runtime.h>
#include <math.h>

#define NVOX 110592   // 48*48*48

typedef _Float16 f16x8 __attribute__((ext_vector_type(8)));
typedef _Float16 f16x4 __attribute__((ext_vector_type(4)));
typedef _Float16 f16x2 __attribute__((ext_vector_type(2)));
typedef float    f32x4 __attribute__((ext_vector_type(4)));

__device__ __forceinline__ float comp4(const float4& v, int j) {
    return j == 0 ? v.x : (j == 1 ? v.y : (j == 2 ? v.z : v.w));
}

// XCD-aware bijective swizzle (8 XCDs; grid % 8 == 0). Neighbor (d,h) rows
// share 2/3 of their halo -> keep them on the same XCD's L2.
__device__ __forceinline__ int xcd_swizzle(int bx, int nwg) {
    int chunk = nwg >> 3;
    return (bx & 7) * chunk + (bx >> 3);
}

// ---------------------------------------------------------------------------
// K0: merged prep.
//  blocks [0,3456): transpose+cast feat/x [32 c][NVOX] f32 -> [NVOX][32 c] f16
//  blocks [3456,3728): weights
//   w1 [64][32][27] f32 -> w1h [64 oc][27 tap][32 ci] f16
//   w2 [216][64] f32    -> w2h [224 oc][64 ci] f16 (rows 216.. zero)
// ---------------------------------------------------------------------------
__global__ __launch_bounds__(256) void k_prep(
    const float* __restrict__ feat, const float* __restrict__ x,
    const float* __restrict__ w1, const float* __restrict__ w2,
    _Float16* __restrict__ featT, _Float16* __restrict__ xT,
    _Float16* __restrict__ w1h, _Float16* __restrict__ w2h)
{
    __shared__ _Float16 tile[64 * 36];
    int bx = blockIdx.x;
    int t = threadIdx.x;

    if (bx >= 3456) {                        // weight prep
        int e = (bx - 3456) * 256 + t;
        if (e < 64 * 32 * 27) {
            int oc = e / 864;
            int r = e - oc * 864;
            int ci = r / 27;
            int tap = r - ci * 27;
            w1h[oc * 864 + tap * 32 + ci] = (_Float16)w1[e];
        }
        int e2 = e - 55296;
        if (e2 >= 0 && e2 < 224 * 64) {
            int oc = e2 >> 6, k = e2 & 63;
            w2h[e2] = (oc < 216) ? (_Float16)w2[oc * 64 + k] : (_Float16)0.f;
        }
        return;
    }

    int which = bx >= 1728;
    int v0 = (which ? bx - 1728 : bx) * 64;
    const float* s = which ? x : feat;
    _Float16* dt = which ? xT : featT;

    for (int i = t; i < 1024; i += 256) {
        int c2 = i >> 6, dv = i & 63;
        f16x2 v;
        v.x = (_Float16)s[(2 * c2) * NVOX + v0 + dv];
        v.y = (_Float16)s[(2 * c2 + 1) * NVOX + v0 + dv];
        *(f16x2*)(tile + dv * 36 + c2 * 2) = v;
    }
    __syncthreads();
    for (int i = t; i < 512; i += 256) {
        int dv = i >> 3, ch = i & 7;
        f16x4 v = *(const f16x4*)(tile + dv * 36 + ch * 4);
        *(f16x4*)(dt + (v0 + dv) * 32 + ch * 4) = v;
    }
}

// ---------------------------------------------------------------------------
// K1: fully fused per (d,h) row of 48 voxels, 512 threads (8 waves).
//  A: stage featT 3x3 halo -> X [450 col][40 f16]          (36 KB)
//  B: conv3x3x3 via MFMA, 6 waves x (px-block, oc-half): B-frag read ONCE
//  C: bias+SiLU -> hl [48 px][72 f16] (aliases X)
//  D: conv1x1 (64->216) via MFMA -> mbuf [8 sub][48 vox][28 f32] (43 KB)
//  E: stage xT halo -> X (overwrites hl) ; softmax(27) in mbuf (384 thr)
//  F: 27-tap combine, 384 thr (tx fastest for coalesced stores):
//     thread = one (w, cq) pair, ALL 8 subs -> xh read once per tap (27/thr,
//     4x fewer LDS reads + cvts than the sp-split version)
// LDS 79,008 B -> 2 blocks/CU.
// ---------------------------------------------------------------------------
__global__ __launch_bounds__(512, 4) void k_main(
    const _Float16* __restrict__ featT, const _Float16* __restrict__ xT,
    const _Float16* __restrict__ w1h, const float* __restrict__ b1,
    const _Float16* __restrict__ w2h, const float* __restrict__ b2,
    float* __restrict__ out)
{
    __shared__ float smem[19752];              // 79,008 B
    float* mbuf = smem;                         // [8][48][28] f32
    _Float16* X  = (_Float16*)(smem + 10752);   // [450][40] f16 staging
    _Float16* hl = (_Float16*)(smem + 10752);   // [48][72] f16 (aliases X)

    int bx = xcd_swizzle(blockIdx.x, gridDim.x);
    int d = bx / 48, hh = bx - d * 48;
    int t = threadIdx.x;

    // ---- phase A: stage featT neighborhood (replicate-clamped)
    for (int i = t; i < 1800; i += 512) {
        int col = i >> 2, chunk = i & 3;        // col = dzdy*50 + px
        int dzdy = col / 50;
        int px = col - dzdy * 50;
        int dz = dzdy / 3, dy = dzdy - dz * 3;
        int zz = min(max(d + dz - 1, 0), 47);
        int yy = min(max(hh + dy - 1, 0), 47);
        int xx = min(max(px - 1, 0), 47);
        int vox = (zz * 48 + yy) * 48 + xx;
        *(f16x8*)(X + col * 40 + chunk * 8) =
            *(const f16x8*)(featT + vox * 32 + chunk * 8);
    }
    __syncthreads();

    int wid = t >> 6;                           // 0..7
    int lane = t & 63;
    int mcol = lane & 15;
    int q = lane >> 4;

    // ---- phase B: conv1 MFMA. 6 waves: wave = (px-block 0..2) x (oc-half)
    f32x4 c1a = {0.f, 0.f, 0.f, 0.f};
    f32x4 c1b = {0.f, 0.f, 0.f, 0.f};
    int pxb = wid >> 1;                         // 0..2 (waves 6,7 idle)
    int och = wid & 1;
    if (wid < 6) {
        const _Float16* wb0 = w1h + (och * 32 + mcol) * 864 + q * 8;
        const _Float16* wb1 = wb0 + 16 * 864;
#pragma unroll 3
        for (int dzdy = 0; dzdy < 9; ++dzdy) {
            const _Float16* brow = X + (dzdy * 50 + pxb * 16 + mcol) * 40 + q * 8;
            const _Float16* wr0 = wb0 + dzdy * 96;
            const _Float16* wr1 = wb1 + dzdy * 96;
#pragma unroll
            for (int dx = 0; dx < 3; ++dx) {
                f16x8 bv = *(const f16x8*)(brow + dx * 40);
                f16x8 a0 = *(const f16x8*)(wr0 + dx * 32);
                f16x8 a1 = *(const f16x8*)(wr1 + dx * 32);
                c1a = __builtin_amdgcn_mfma_f32_16x16x32_f16(a0, bv, c1a, 0, 0, 0);
                c1b = __builtin_amdgcn_mfma_f32_16x16x32_f16(a1, bv, c1b, 0, 0, 0);
            }
        }
    }
    __syncthreads();                            // all X reads done

    // ---- phase C: bias + SiLU -> hl (aliases X head)
    if (wid < 6) {
        int pxv = pxb * 16 + mcol;              // D: col = lane&15
        float4 bva = ((const float4*)b1)[(och * 2) * 4 + q];
        float4 bvb = ((const float4*)b1)[(och * 2 + 1) * 4 + q];
        f16x4 o; float s;
        s = c1a[0] + bva.x; o.x = (_Float16)(s / (1.f + __expf(-s)));
        s = c1a[1] + bva.y; o.y = (_Float16)(s / (1.f + __expf(-s)));
        s = c1a[2] + bva.z; o.z = (_Float16)(s / (1.f + __expf(-s)));
        s = c1a[3] + bva.w; o.w = (_Float16)(s / (1.f + __expf(-s)));
        *(f16x4*)(hl + pxv * 72 + och * 32 + q * 4) = o;
        s = c1b[0] + bvb.x; o.x = (_Float16)(s / (1.f + __expf(-s)));
        s = c1b[1] + bvb.y; o.y = (_Float16)(s / (1.f + __expf(-s)));
        s = c1b[2] + bvb.z; o.z = (_Float16)(s / (1.f + __expf(-s)));
        s = c1b[3] + bvb.w; o.w = (_Float16)(s / (1.f + __expf(-s)));
        *(f16x4*)(hl + pxv * 72 + och * 32 + 16 + q * 4) = o;
    }
    __syncthreads();                            // hl complete

    // ---- phase D: conv2 MFMA, 42 tiles (14 mt x 3 nt) over 8 waves
    for (int tt = wid; tt < 42; tt += 8) {
        int mt = tt / 3, nt = tt - mt * 3;
        float bias[4];
#pragma unroll
        for (int rr = 0; rr < 4; ++rr) {
            int oc = mt * 16 + q * 4 + rr;
            bias[rr] = (oc < 216) ? b2[oc] : 0.f;
        }
        f32x4 acc = {bias[0], bias[1], bias[2], bias[3]};
#pragma unroll
        for (int ks = 0; ks < 2; ++ks) {
            f16x8 av = *(const f16x8*)(w2h + (mt * 16 + mcol) * 64 + ks * 32 + q * 8);
            f16x8 bv = *(const f16x8*)(hl + (nt * 16 + mcol) * 72 + ks * 32 + q * 8);
            acc = __builtin_amdgcn_mfma_f32_16x16x32_f16(av, bv, acc, 0, 0, 0);
        }
        int vox = nt * 16 + mcol;
#pragma unroll
        for (int rr = 0; rr < 4; ++rr) {
            int oc = mt * 16 + q * 4 + rr;
            if (oc < 216) {
                int sub = oc / 27;
                int n = oc - sub * 27;
                mbuf[(sub * 48 + vox) * 28 + n] = acc[rr];
            }
        }
    }
    __syncthreads();                            // mbuf complete, hl dead

    // ---- phase E: stage xT halo into X (overwrites hl) + softmax in mbuf
    for (int i = t; i < 1800; i += 512) {
        int col = i >> 2, chunk = i & 3;
        int dzdy = col / 50;
        int px = col - dzdy * 50;
        int dz = dzdy / 3, dy = dzdy - dz * 3;
        int zz = min(max(d + dz - 1, 0), 47);
        int yy = min(max(hh + dy - 1, 0), 47);
        int xx = min(max(px - 1, 0), 47);
        int vox = (zz * 48 + yy) * 48 + xx;
        *(f16x8*)(X + col * 40 + chunk * 8) =
            *(const f16x8*)(xT + vox * 32 + chunk * 8);
    }
    if (t < 384) {                              // 8 sub x 48 vox rows
        int sub = t / 48;
        int vox = t - sub * 48;
        float4* p4p = (float4*)(mbuf + (sub * 48 + vox) * 28);
        float4 v[7];
#pragma unroll
        for (int g = 0; g < 7; ++g) v[g] = p4p[g];
        float mx = fmaxf(fmaxf(v[6].x, v[6].y), v[6].z);
#pragma unroll
        for (int g = 0; g < 6; ++g)
            mx = fmaxf(mx, fmaxf(fmaxf(v[g].x, v[g].y), fmaxf(v[g].z, v[g].w)));
        float s = 0.f;
#pragma unroll
        for (int g = 0; g < 7; ++g) {
            v[g].x = __expf(v[g].x - mx);
            v[g].y = __expf(v[g].y - mx);
            v[g].z = __expf(v[g].z - mx);
            v[g].w = __expf(v[g].w - mx);
        }
        v[6].w = 0.f;                           // tap 27 pad
#pragma unroll
        for (int g = 0; g < 7; ++g) s += v[g].x + v[g].y + v[g].z + v[g].w;
        float inv = 1.f / s;
#pragma unroll
        for (int g = 0; g < 7; ++g) {
            v[g].x *= inv; v[g].y *= inv; v[g].z *= inv; v[g].w *= inv;
            p4p[g] = v[g];
        }
    }
    __syncthreads();

    // ---- phase F: 384 thr, tx FASTEST (coalesced stores like R3):
    // thread = (tx 8)+(cq 8)+(half 2)+(wig 3); owns (w, cq), all 8 subs.
    // out[c][2d+i][2h+j][2w+k] = sum_n p[(i*2+j)*2+k][w][n] * x[c][nb(w,n)]
    if (t < 384) {
        int tx = t & 7;
        int cq = (t >> 3) & 7;
        int half = (t >> 6) & 1;
        int wig = t >> 7;                       // 0..2
        int w = half * 24 + wig * 8 + tx;

        float acc[8][4];
#pragma unroll
        for (int sub = 0; sub < 8; ++sub)
#pragma unroll
            for (int cc = 0; cc < 4; ++cc) acc[sub][cc] = 0.f;

        const float4* smem4 = (const float4*)smem;
#pragma unroll
        for (int g = 0; g < 7; ++g) {
            float4 p[8];
#pragma unroll
            for (int sub = 0; sub < 8; ++sub)
                p[sub] = smem4[(sub * 48 + w) * 7 + g];   // bcast across cq
#pragma unroll
            for (int j = 0; j < 4; ++j) {
                int n = g * 4 + j;
                if (n < 27) {
                    int r = n / 3;              // dzdy (compile-time)
                    int dx = n - r * 3;
                    int col = r * 50 + w + dx;  // px = w+dx (clamped at stage)
                    f16x4 xr = *(const f16x4*)(X + col * 40 + cq * 4);
                    float4 xv = make_float4((float)xr.x, (float)xr.y,
                                            (float)xr.z, (float)xr.w);
#pragma unroll
                    for (int sub = 0; sub < 8; ++sub) {
                        float pv = comp4(p[sub], j);
                        acc[sub][0] = fmaf(xv.x, pv, acc[sub][0]);
                        acc[sub][1] = fmaf(xv.y, pv, acc[sub][1]);
                        acc[sub][2] = fmaf(xv.z, pv, acc[sub][2]);
                        acc[sub][3] = fmaf(xv.w, pv, acc[sub][3]);
                    }
                }
            }
        }

#pragma unroll
        for (int ij = 0; ij < 4; ++ij) {
            int i_ = ij >> 1, j_ = ij & 1;
            int rowz = 2 * d + i_;
            int rowy = 2 * hh + j_;
            int s0 = ij * 2;                    // sub for k=0
#pragma unroll
            for (int cc = 0; cc < 4; ++cc) {
                int c = cq * 4 + cc;
                float2 v;
                v.x = acc[s0][cc];              // k = 0
                v.y = acc[s0 + 1][cc];          // k = 1
                *(float2*)(out + (((size_t)c * 96 + rowz) * 96 + rowy) * 96 + 2 * w) = v;
            }
        }
    }
}

extern "C" void kernel_launch(void* const* d_in, const int* in_sizes, int n_in,
                              void* d_out, int out_size, void* d_ws, size_t ws_size,
                              hipStream_t stream) {
    const float* x    = (const float*)d_in[0];
    const float* feat = (const float*)d_in[1];
    const float* w1   = (const float*)d_in[2];
    const float* b1   = (const float*)d_in[3];
    const float* w2   = (const float*)d_in[4];
    const float* b2   = (const float*)d_in[5];
    float* out = (float*)d_out;

    _Float16* w1h   = (_Float16*)d_ws;                       //    110,592 B
    _Float16* w2h   = (_Float16*)((char*)d_ws + 110592);     //     28,672 B
    _Float16* featT = (_Float16*)((char*)d_ws + 139264);     //  7,077,888 B
    _Float16* xT    = (_Float16*)((char*)d_ws + 7217152);    //  7,077,888 B

    k_prep<<<3728, 256, 0, stream>>>(feat, x, w1, w2, featT, xT, w1h, w2h);
    k_main<<<2304, 512, 0, stream>>>(featT, xT, w1h, b1, w2h, b2, out);
}

// Round 7
// 307.743 us; speedup vs baseline: 1.0038x; 1.0038x over previous
//
#include <hip/hip_runtime.h>
#include <math.h>

#define NVOX 110592   // 48*48*48

typedef _Float16 f16x8 __attribute__((ext_vector_type(8)));
typedef _Float16 f16x4 __attribute__((ext_vector_type(4)));
typedef _Float16 f16x2 __attribute__((ext_vector_type(2)));
typedef float    f32x4 __attribute__((ext_vector_type(4)));

__device__ __forceinline__ float comp4(const float4& v, int j) {
    return j == 0 ? v.x : (j == 1 ? v.y : (j == 2 ? v.z : v.w));
}

// XCD-aware bijective swizzle (8 XCDs; grid % 8 == 0). Neighbor (d,h) rows
// share 2/3 of their halo -> keep them on the same XCD's L2.
__device__ __forceinline__ int xcd_swizzle(int bx, int nwg) {
    int chunk = nwg >> 3;
    return (bx & 7) * chunk + (bx >> 3);
}

// ---------------------------------------------------------------------------
// K0: merged prep.
//  blocks [0,3456): transpose+cast feat/x [32 c][NVOX] f32 -> [NVOX][32 c] f16
//  blocks [3456,3728): weights
//   w1 [64][32][27] f32 -> w1h [64 oc][27 tap][32 ci] f16
//   w2 [216][64] f32    -> w2h [224 oc][64 ci] f16 (rows 216.. zero)
// ---------------------------------------------------------------------------
__global__ __launch_bounds__(256) void k_prep(
    const float* __restrict__ feat, const float* __restrict__ x,
    const float* __restrict__ w1, const float* __restrict__ w2,
    _Float16* __restrict__ featT, _Float16* __restrict__ xT,
    _Float16* __restrict__ w1h, _Float16* __restrict__ w2h)
{
    __shared__ _Float16 tile[64 * 36];
    int bx = blockIdx.x;
    int t = threadIdx.x;

    if (bx >= 3456) {                        // weight prep
        int e = (bx - 3456) * 256 + t;
        if (e < 64 * 32 * 27) {
            int oc = e / 864;
            int r = e - oc * 864;
            int ci = r / 27;
            int tap = r - ci * 27;
            w1h[oc * 864 + tap * 32 + ci] = (_Float16)w1[e];
        }
        int e2 = e - 55296;
        if (e2 >= 0 && e2 < 224 * 64) {
            int oc = e2 >> 6, k = e2 & 63;
            w2h[e2] = (oc < 216) ? (_Float16)w2[oc * 64 + k] : (_Float16)0.f;
        }
        return;
    }

    int which = bx >= 1728;
    int v0 = (which ? bx - 1728 : bx) * 64;
    const float* s = which ? x : feat;
    _Float16* dt = which ? xT : featT;

    for (int i = t; i < 1024; i += 256) {
        int c2 = i >> 6, dv = i & 63;
        f16x2 v;
        v.x = (_Float16)s[(2 * c2) * NVOX + v0 + dv];
        v.y = (_Float16)s[(2 * c2 + 1) * NVOX + v0 + dv];
        *(f16x2*)(tile + dv * 36 + c2 * 2) = v;
    }
    __syncthreads();
    for (int i = t; i < 512; i += 256) {
        int dv = i >> 3, ch = i & 7;
        f16x4 v = *(const f16x4*)(tile + dv * 36 + ch * 4);
        *(f16x4*)(dt + (v0 + dv) * 32 + ch * 4) = v;
    }
}

// ---------------------------------------------------------------------------
// K1: fully fused per (d,h) row of 48 voxels, 512 threads (8 waves).
//  A: stage featT 3x3 halo -> X [450 col][40 f16]          (36 KB)
//  B: conv3x3x3 via MFMA, 6 waves x (px-block, oc-half): B-frag read ONCE
//  C: bias+SiLU -> hl [48 px][72 f16] (aliases X)
//  D: conv1x1 (64->216) via MFMA -> mbuf [8 sub][48 vox][28 f32] (43 KB)
//  E: stage xT halo -> X (overwrites hl) ; softmax(27) in mbuf (384 thr)
//  F: 27-tap combine, 384 thr = (tx 16)x(cq 8)x(wgrp 3):
//     thread owns (w, cq-quad), ALL 8 subs -> 1 xh read per tap per wave;
//     16 lanes span 16 consecutive w -> every 128B out line fully written
//     by ONE wave in adjacent instructions (no partial-line RMW).
// LDS 79,008 B -> 2 blocks/CU.
// ---------------------------------------------------------------------------
__global__ __launch_bounds__(512, 4) void k_main(
    const _Float16* __restrict__ featT, const _Float16* __restrict__ xT,
    const _Float16* __restrict__ w1h, const float* __restrict__ b1,
    const _Float16* __restrict__ w2h, const float* __restrict__ b2,
    float* __restrict__ out)
{
    __shared__ float smem[19752];              // 79,008 B
    float* mbuf = smem;                         // [8][48][28] f32
    _Float16* X  = (_Float16*)(smem + 10752);   // [450][40] f16 staging
    _Float16* hl = (_Float16*)(smem + 10752);   // [48][72] f16 (aliases X)

    int bx = xcd_swizzle(blockIdx.x, gridDim.x);
    int d = bx / 48, hh = bx - d * 48;
    int t = threadIdx.x;

    // ---- phase A: stage featT neighborhood (replicate-clamped)
    for (int i = t; i < 1800; i += 512) {
        int col = i >> 2, chunk = i & 3;        // col = dzdy*50 + px
        int dzdy = col / 50;
        int px = col - dzdy * 50;
        int dz = dzdy / 3, dy = dzdy - dz * 3;
        int zz = min(max(d + dz - 1, 0), 47);
        int yy = min(max(hh + dy - 1, 0), 47);
        int xx = min(max(px - 1, 0), 47);
        int vox = (zz * 48 + yy) * 48 + xx;
        *(f16x8*)(X + col * 40 + chunk * 8) =
            *(const f16x8*)(featT + vox * 32 + chunk * 8);
    }
    __syncthreads();

    int wid = t >> 6;                           // 0..7
    int lane = t & 63;
    int mcol = lane & 15;
    int q = lane >> 4;

    // ---- phase B: conv1 MFMA. 6 waves: wave = (px-block 0..2) x (oc-half)
    f32x4 c1a = {0.f, 0.f, 0.f, 0.f};
    f32x4 c1b = {0.f, 0.f, 0.f, 0.f};
    int pxb = wid >> 1;                         // 0..2 (waves 6,7 idle)
    int och = wid & 1;
    if (wid < 6) {
        const _Float16* wb0 = w1h + (och * 32 + mcol) * 864 + q * 8;
        const _Float16* wb1 = wb0 + 16 * 864;
#pragma unroll 3
        for (int dzdy = 0; dzdy < 9; ++dzdy) {
            const _Float16* brow = X + (dzdy * 50 + pxb * 16 + mcol) * 40 + q * 8;
            const _Float16* wr0 = wb0 + dzdy * 96;
            const _Float16* wr1 = wb1 + dzdy * 96;
#pragma unroll
            for (int dx = 0; dx < 3; ++dx) {
                f16x8 bv = *(const f16x8*)(brow + dx * 40);
                f16x8 a0 = *(const f16x8*)(wr0 + dx * 32);
                f16x8 a1 = *(const f16x8*)(wr1 + dx * 32);
                c1a = __builtin_amdgcn_mfma_f32_16x16x32_f16(a0, bv, c1a, 0, 0, 0);
                c1b = __builtin_amdgcn_mfma_f32_16x16x32_f16(a1, bv, c1b, 0, 0, 0);
            }
        }
    }
    __syncthreads();                            // all X reads done

    // ---- phase C: bias + SiLU -> hl (aliases X head)
    if (wid < 6) {
        int pxv = pxb * 16 + mcol;              // D: col = lane&15
        float4 bva = ((const float4*)b1)[(och * 2) * 4 + q];
        float4 bvb = ((const float4*)b1)[(och * 2 + 1) * 4 + q];
        f16x4 o; float s;
        s = c1a[0] + bva.x; o.x = (_Float16)(s / (1.f + __expf(-s)));
        s = c1a[1] + bva.y; o.y = (_Float16)(s / (1.f + __expf(-s)));
        s = c1a[2] + bva.z; o.z = (_Float16)(s / (1.f + __expf(-s)));
        s = c1a[3] + bva.w; o.w = (_Float16)(s / (1.f + __expf(-s)));
        *(f16x4*)(hl + pxv * 72 + och * 32 + q * 4) = o;
        s = c1b[0] + bvb.x; o.x = (_Float16)(s / (1.f + __expf(-s)));
        s = c1b[1] + bvb.y; o.y = (_Float16)(s / (1.f + __expf(-s)));
        s = c1b[2] + bvb.z; o.z = (_Float16)(s / (1.f + __expf(-s)));
        s = c1b[3] + bvb.w; o.w = (_Float16)(s / (1.f + __expf(-s)));
        *(f16x4*)(hl + pxv * 72 + och * 32 + 16 + q * 4) = o;
    }
    __syncthreads();                            // hl complete

    // ---- phase D: conv2 MFMA, 42 tiles (14 mt x 3 nt) over 8 waves
    for (int tt = wid; tt < 42; tt += 8) {
        int mt = tt / 3, nt = tt - mt * 3;
        float bias[4];
#pragma unroll
        for (int rr = 0; rr < 4; ++rr) {
            int oc = mt * 16 + q * 4 + rr;
            bias[rr] = (oc < 216) ? b2[oc] : 0.f;
        }
        f32x4 acc = {bias[0], bias[1], bias[2], bias[3]};
#pragma unroll
        for (int ks = 0; ks < 2; ++ks) {
            f16x8 av = *(const f16x8*)(w2h + (mt * 16 + mcol) * 64 + ks * 32 + q * 8);
            f16x8 bv = *(const f16x8*)(hl + (nt * 16 + mcol) * 72 + ks * 32 + q * 8);
            acc = __builtin_amdgcn_mfma_f32_16x16x32_f16(av, bv, acc, 0, 0, 0);
        }
        int vox = nt * 16 + mcol;
#pragma unroll
        for (int rr = 0; rr < 4; ++rr) {
            int oc = mt * 16 + q * 4 + rr;
            if (oc < 216) {
                int sub = oc / 27;
                int n = oc - sub * 27;
                mbuf[(sub * 48 + vox) * 28 + n] = acc[rr];
            }
        }
    }
    __syncthreads();                            // mbuf complete, hl dead

    // ---- phase E: stage xT halo into X (overwrites hl) + softmax in mbuf
    for (int i = t; i < 1800; i += 512) {
        int col = i >> 2, chunk = i & 3;
        int dzdy = col / 50;
        int px = col - dzdy * 50;
        int dz = dzdy / 3, dy = dzdy - dz * 3;
        int zz = min(max(d + dz - 1, 0), 47);
        int yy = min(max(hh + dy - 1, 0), 47);
        int xx = min(max(px - 1, 0), 47);
        int vox = (zz * 48 + yy) * 48 + xx;
        *(f16x8*)(X + col * 40 + chunk * 8) =
            *(const f16x8*)(xT + vox * 32 + chunk * 8);
    }
    if (t < 384) {                              // 8 sub x 48 vox rows
        int sub = t / 48;
        int vox = t - sub * 48;
        float4* p4p = (float4*)(mbuf + (sub * 48 + vox) * 28);
        float4 v[7];
#pragma unroll
        for (int g = 0; g < 7; ++g) v[g] = p4p[g];
        float mx = fmaxf(fmaxf(v[6].x, v[6].y), v[6].z);
#pragma unroll
        for (int g = 0; g < 6; ++g)
            mx = fmaxf(mx, fmaxf(fmaxf(v[g].x, v[g].y), fmaxf(v[g].z, v[g].w)));
        float s = 0.f;
#pragma unroll
        for (int g = 0; g < 7; ++g) {
            v[g].x = __expf(v[g].x - mx);
            v[g].y = __expf(v[g].y - mx);
            v[g].z = __expf(v[g].z - mx);
            v[g].w = __expf(v[g].w - mx);
        }
        v[6].w = 0.f;                           // tap 27 pad
#pragma unroll
        for (int g = 0; g < 7; ++g) s += v[g].x + v[g].y + v[g].z + v[g].w;
        float inv = 1.f / s;
#pragma unroll
        for (int g = 0; g < 7; ++g) {
            v[g].x *= inv; v[g].y *= inv; v[g].z *= inv; v[g].w *= inv;
            p4p[g] = v[g];
        }
    }
    __syncthreads();

    // ---- phase F: 384 thr = (tx 16) x (cq 8) x (wgrp 3); w = wgrp*16+tx.
    // Lanes 0-15 of each store span 16 consecutive w -> full 128B lines.
    // out[c][2d+i][2h+j][2w+k] = sum_n p[(i*2+j)*2+k][w][n] * x[c][nb(w,n)]
    if (t < 384) {
        int tx = t & 15;
        int cq = (t >> 4) & 7;
        int wgrp = t >> 7;                      // 0..2
        int w = wgrp * 16 + tx;

        float acc[8][4];
#pragma unroll
        for (int sub = 0; sub < 8; ++sub)
#pragma unroll
            for (int cc = 0; cc < 4; ++cc) acc[sub][cc] = 0.f;

        const float4* smem4 = (const float4*)smem;
#pragma unroll
        for (int g = 0; g < 7; ++g) {
            float4 p[8];
#pragma unroll
            for (int sub = 0; sub < 8; ++sub)
                p[sub] = smem4[(sub * 48 + w) * 7 + g];   // bcast across cq
#pragma unroll
            for (int j = 0; j < 4; ++j) {
                int n = g * 4 + j;
                if (n < 27) {
                    int r = n / 3;              // dzdy (compile-time)
                    int dx = n - r * 3;
                    int col = r * 50 + w + dx;  // px = w+dx (clamped at stage)
                    f16x4 xr = *(const f16x4*)(X + col * 40 + cq * 4);
                    float4 xv = make_float4((float)xr.x, (float)xr.y,
                                            (float)xr.z, (float)xr.w);
#pragma unroll
                    for (int sub = 0; sub < 8; ++sub) {
                        float pv = comp4(p[sub], j);
                        acc[sub][0] = fmaf(xv.x, pv, acc[sub][0]);
                        acc[sub][1] = fmaf(xv.y, pv, acc[sub][1]);
                        acc[sub][2] = fmaf(xv.z, pv, acc[sub][2]);
                        acc[sub][3] = fmaf(xv.w, pv, acc[sub][3]);
                    }
                }
            }
        }

#pragma unroll
        for (int ij = 0; ij < 4; ++ij) {
            int i_ = ij >> 1, j_ = ij & 1;
            int rowz = 2 * d + i_;
            int rowy = 2 * hh + j_;
            int s0 = ij * 2;                    // sub for k=0
#pragma unroll
            for (int cc = 0; cc < 4; ++cc) {
                int c = cq * 4 + cc;
                float2 v;
                v.x = acc[s0][cc];              // k = 0
                v.y = acc[s0 + 1][cc];          // k = 1
                *(float2*)(out + (((size_t)c * 96 + rowz) * 96 + rowy) * 96 + 2 * w) = v;
            }
        }
    }
}

extern "C" void kernel_launch(void* const* d_in, const int* in_sizes, int n_in,
                              void* d_out, int out_size, void* d_ws, size_t ws_size,
                              hipStream_t stream) {
    const float* x    = (const float*)d_in[0];
    const float* feat = (const float*)d_in[1];
    const float* w1   = (const float*)d_in[2];
    const float* b1   = (const float*)d_in[3];
    const float* w2   = (const float*)d_in[4];
    const float* b2   = (const float*)d_in[5];
    float* out = (float*)d_out;

    _Float16* w1h   = (_Float16*)d_ws;                       //    110,592 B
    _Float16* w2h   = (_Float16*)((char*)d_ws + 110592);     //     28,672 B
    _Float16* featT = (_Float16*)((char*)d_ws + 139264);     //  7,077,888 B
    _Float16* xT    = (_Float16*)((char*)d_ws + 7217152);    //  7,077,888 B

    k_prep<<<3728, 256, 0, stream>>>(feat, x, w1, w2, featT, xT, w1h, w2h);
    k_main<<<2304, 512, 0, stream>>>(featT, xT, w1h, b1, w2h, b2, out);
}

// Round 8
// 304.247 us; speedup vs baseline: 1.0153x; 1.0115x over previous
//
#include <hip/hip_runtime.h>
#include <math.h>

#define NVOX 110592   // 48*48*48

typedef _Float16 f16x8 __attribute__((ext_vector_type(8)));
typedef _Float16 f16x4 __attribute__((ext_vector_type(4)));
typedef _Float16 f16x2 __attribute__((ext_vector_type(2)));
typedef float    f32x4 __attribute__((ext_vector_type(4)));

__device__ __forceinline__ float comp4(const float4& v, int j) {
    return j == 0 ? v.x : (j == 1 ? v.y : (j == 2 ? v.z : v.w));
}

// XCD-aware bijective swizzle (8 XCDs; grid % 8 == 0). Neighbor (d,h) rows
// share 2/3 of their halo -> keep them on the same XCD's L2.
__device__ __forceinline__ int xcd_swizzle(int bx, int nwg) {
    int chunk = nwg >> 3;
    return (bx & 7) * chunk + (bx >> 3);
}

// ---------------------------------------------------------------------------
// K0: merged prep.
//  blocks [0,3456): transpose+cast feat/x [32 c][NVOX] f32 -> [NVOX][32 c] f16
//  blocks [3456,3728): weights
//   w1 [64][32][27] f32 -> w1h [64 oc][27 tap][32 ci] f16
//   w2 [216][64] f32    -> w2h [224 oc][64 ci] f16 (rows 216.. zero)
// ---------------------------------------------------------------------------
__global__ __launch_bounds__(256) void k_prep(
    const float* __restrict__ feat, const float* __restrict__ x,
    const float* __restrict__ w1, const float* __restrict__ w2,
    _Float16* __restrict__ featT, _Float16* __restrict__ xT,
    _Float16* __restrict__ w1h, _Float16* __restrict__ w2h)
{
    __shared__ _Float16 tile[64 * 36];
    int bx = blockIdx.x;
    int t = threadIdx.x;

    if (bx >= 3456) {                        // weight prep
        int e = (bx - 3456) * 256 + t;
        if (e < 64 * 32 * 27) {
            int oc = e / 864;
            int r = e - oc * 864;
            int ci = r / 27;
            int tap = r - ci * 27;
            w1h[oc * 864 + tap * 32 + ci] = (_Float16)w1[e];
        }
        int e2 = e - 55296;
        if (e2 >= 0 && e2 < 224 * 64) {
            int oc = e2 >> 6, k = e2 & 63;
            w2h[e2] = (oc < 216) ? (_Float16)w2[oc * 64 + k] : (_Float16)0.f;
        }
        return;
    }

    int which = bx >= 1728;
    int v0 = (which ? bx - 1728 : bx) * 64;
    const float* s = which ? x : feat;
    _Float16* dt = which ? xT : featT;

    for (int i = t; i < 1024; i += 256) {
        int c2 = i >> 6, dv = i & 63;
        f16x2 v;
        v.x = (_Float16)s[(2 * c2) * NVOX + v0 + dv];
        v.y = (_Float16)s[(2 * c2 + 1) * NVOX + v0 + dv];
        *(f16x2*)(tile + dv * 36 + c2 * 2) = v;
    }
    __syncthreads();
    for (int i = t; i < 512; i += 256) {
        int dv = i >> 3, ch = i & 7;
        f16x4 v = *(const f16x4*)(tile + dv * 36 + ch * 4);
        *(f16x4*)(dt + (v0 + dv) * 32 + ch * 4) = v;
    }
}

// ---------------------------------------------------------------------------
// K1: fully fused per (d,h) row of 48 voxels, 512 threads (8 waves).
// Phases A-E are BYTE-IDENTICAL to the round-3 kernel (measured: 130 us,
// FETCH 28.7 MB, WRITE 148 MB).  Only phase F is swapped for the
// low-LDS-read mapping (A/B isolation of the traffic anomaly).
//  A: stage featT 3x3 halo -> X [450 col][40 f16]          (36 KB)
//  B: conv3x3x3 + SiLU via MFMA, 8 waves: wave w -> oc strip w&3,
//     px blocks {0,2} (waves 0-3) / {1} (waves 4-7)
//  C: bias+SiLU -> hl [48 px][72 f16] (aliases X)
//  D: conv1x1 (64->216) via MFMA -> mbuf [8 sub][48 vox][28 f32] (43 KB)
//  E: stage xT halo -> X (overwrites hl) ; softmax(27) in mbuf (384 thr)
//  F: 27-tap combine, 384 thr = (tx 16)x(cq 8)x(wgrp 3): thread owns
//     (w, cq-quad), ALL 8 subs -> 27 xh reads/thread (1/4 of the R3 F),
//     full 128B out lines per store instruction.
// LDS 79,008 B -> 2 blocks/CU.
// ---------------------------------------------------------------------------
__global__ __launch_bounds__(512, 4) void k_main(
    const _Float16* __restrict__ featT, const _Float16* __restrict__ xT,
    const _Float16* __restrict__ w1h, const float* __restrict__ b1,
    const _Float16* __restrict__ w2h, const float* __restrict__ b2,
    float* __restrict__ out)
{
    __shared__ float smem[19752];              // 79,008 B
    float* mbuf = smem;                         // [8][48][28] f32
    _Float16* X  = (_Float16*)(smem + 10752);   // [450][40] f16 staging
    _Float16* hl = (_Float16*)(smem + 10752);   // [48][72] f16 (aliases X)

    int bx = xcd_swizzle(blockIdx.x, gridDim.x);
    int d = bx / 48, hh = bx - d * 48;
    int t = threadIdx.x;

    // ---- phase A: stage featT neighborhood (replicate-clamped)
    for (int i = t; i < 1800; i += 512) {
        int col = i >> 2, chunk = i & 3;        // col = dzdy*50 + px
        int dzdy = col / 50;
        int px = col - dzdy * 50;
        int dz = dzdy / 3, dy = dzdy - dz * 3;
        int zz = min(max(d + dz - 1, 0), 47);
        int yy = min(max(hh + dy - 1, 0), 47);
        int xx = min(max(px - 1, 0), 47);
        int vox = (zz * 48 + yy) * 48 + xx;
        *(f16x8*)(X + col * 40 + chunk * 8) =
            *(const f16x8*)(featT + vox * 32 + chunk * 8);
    }
    __syncthreads();

    int wid = t >> 6;                           // 0..7
    int lane = t & 63;
    int mcol = lane & 15;
    int q = lane >> 4;
    int ocs = wid & 3;                          // oc strip for conv1

    // ---- phase B: conv1 MFMA. waves 0-3: px blocks {0,2}; waves 4-7: {1}
    f32x4 c1a = {0.f, 0.f, 0.f, 0.f};
    f32x4 c1b = {0.f, 0.f, 0.f, 0.f};
    {
        const _Float16* wbase = w1h + (ocs * 16 + mcol) * 864 + q * 8;
#pragma unroll 3
        for (int dzdy = 0; dzdy < 9; ++dzdy) {
            const _Float16* brow = X + (dzdy * 50 + mcol) * 40 + q * 8;
            const _Float16* wrow = wbase + dzdy * 96;
#pragma unroll
            for (int dx = 0; dx < 3; ++dx) {
                f16x8 av = *(const f16x8*)(wrow + dx * 32);
                const _Float16* bb = brow + dx * 40;
                if (wid < 4) {
                    f16x8 b0 = *(const f16x8*)(bb);
                    f16x8 b2v = *(const f16x8*)(bb + 32 * 40);
                    c1a = __builtin_amdgcn_mfma_f32_16x16x32_f16(av, b0, c1a, 0, 0, 0);
                    c1b = __builtin_amdgcn_mfma_f32_16x16x32_f16(av, b2v, c1b, 0, 0, 0);
                } else {
                    f16x8 b1v = *(const f16x8*)(bb + 16 * 40);
                    c1a = __builtin_amdgcn_mfma_f32_16x16x32_f16(av, b1v, c1a, 0, 0, 0);
                }
            }
        }
    }
    __syncthreads();                            // all X reads done

    // ---- phase C: bias + SiLU -> hl (aliases X head)
    {
        float4 bv = ((const float4*)b1)[ocs * 4 + q];
        int pxb0 = (wid < 4) ? 0 : 1;
        int px0 = pxb0 * 16 + mcol;
        f16x4 o; float s;
        s = c1a[0] + bv.x; o.x = (_Float16)(s / (1.f + __expf(-s)));
        s = c1a[1] + bv.y; o.y = (_Float16)(s / (1.f + __expf(-s)));
        s = c1a[2] + bv.z; o.z = (_Float16)(s / (1.f + __expf(-s)));
        s = c1a[3] + bv.w; o.w = (_Float16)(s / (1.f + __expf(-s)));
        *(f16x4*)(hl + px0 * 72 + ocs * 16 + q * 4) = o;
        if (wid < 4) {
            int px1 = 32 + mcol;
            s = c1b[0] + bv.x; o.x = (_Float16)(s / (1.f + __expf(-s)));
            s = c1b[1] + bv.y; o.y = (_Float16)(s / (1.f + __expf(-s)));
            s = c1b[2] + bv.z; o.z = (_Float16)(s / (1.f + __expf(-s)));
            s = c1b[3] + bv.w; o.w = (_Float16)(s / (1.f + __expf(-s)));
            *(f16x4*)(hl + px1 * 72 + ocs * 16 + q * 4) = o;
        }
    }
    __syncthreads();                            // hl complete

    // ---- phase D: conv2 MFMA, 42 tiles (14 mt x 3 nt) over 8 waves
    for (int tt = wid; tt < 42; tt += 8) {
        int mt = tt / 3, nt = tt - mt * 3;
        float bias[4];
#pragma unroll
        for (int rr = 0; rr < 4; ++rr) {
            int oc = mt * 16 + q * 4 + rr;
            bias[rr] = (oc < 216) ? b2[oc] : 0.f;
        }
        f32x4 acc = {bias[0], bias[1], bias[2], bias[3]};
#pragma unroll
        for (int ks = 0; ks < 2; ++ks) {
            f16x8 av = *(const f16x8*)(w2h + (mt * 16 + mcol) * 64 + ks * 32 + q * 8);
            f16x8 bv = *(const f16x8*)(hl + (nt * 16 + mcol) * 72 + ks * 32 + q * 8);
            acc = __builtin_amdgcn_mfma_f32_16x16x32_f16(av, bv, acc, 0, 0, 0);
        }
        int vox = nt * 16 + mcol;
#pragma unroll
        for (int rr = 0; rr < 4; ++rr) {
            int oc = mt * 16 + q * 4 + rr;
            if (oc < 216) {
                int sub = oc / 27;
                int n = oc - sub * 27;
                mbuf[(sub * 48 + vox) * 28 + n] = acc[rr];
            }
        }
    }
    __syncthreads();                            // mbuf complete, hl dead

    // ---- phase E: stage xT halo into X (overwrites hl) + softmax in mbuf
    for (int i = t; i < 1800; i += 512) {
        int col = i >> 2, chunk = i & 3;
        int dzdy = col / 50;
        int px = col - dzdy * 50;
        int dz = dzdy / 3, dy = dzdy - dz * 3;
        int zz = min(max(d + dz - 1, 0), 47);
        int yy = min(max(hh + dy - 1, 0), 47);
        int xx = min(max(px - 1, 0), 47);
        int vox = (zz * 48 + yy) * 48 + xx;
        *(f16x8*)(X + col * 40 + chunk * 8) =
            *(const f16x8*)(xT + vox * 32 + chunk * 8);
    }
    if (t < 384) {                              // 8 sub x 48 vox rows
        int sub = t / 48;
        int vox = t - sub * 48;
        float4* p4p = (float4*)(mbuf + (sub * 48 + vox) * 28);
        float4 v[7];
#pragma unroll
        for (int g = 0; g < 7; ++g) v[g] = p4p[g];
        float mx = fmaxf(fmaxf(v[6].x, v[6].y), v[6].z);
#pragma unroll
        for (int g = 0; g < 6; ++g)
            mx = fmaxf(mx, fmaxf(fmaxf(v[g].x, v[g].y), fmaxf(v[g].z, v[g].w)));
        float s = 0.f;
#pragma unroll
        for (int g = 0; g < 7; ++g) {
            v[g].x = __expf(v[g].x - mx);
            v[g].y = __expf(v[g].y - mx);
            v[g].z = __expf(v[g].z - mx);
            v[g].w = __expf(v[g].w - mx);
        }
        v[6].w = 0.f;                           // tap 27 pad
#pragma unroll
        for (int g = 0; g < 7; ++g) s += v[g].x + v[g].y + v[g].z + v[g].w;
        float inv = 1.f / s;
#pragma unroll
        for (int g = 0; g < 7; ++g) {
            v[g].x *= inv; v[g].y *= inv; v[g].z *= inv; v[g].w *= inv;
            p4p[g] = v[g];
        }
    }
    __syncthreads();

    // ---- phase F (swapped in): 384 thr = (tx 16) x (cq 8) x (wgrp 3).
    // w = wgrp*16+tx; thread owns (w, cq-quad), all 8 subs.
    // out[c][2d+i][2h+j][2w+k] = sum_n p[(i*2+j)*2+k][w][n] * x[c][nb(w,n)]
    if (t < 384) {
        int tx = t & 15;
        int cq = (t >> 4) & 7;
        int wgrp = t >> 7;                      // 0..2
        int w = wgrp * 16 + tx;

        float acc[8][4];
#pragma unroll
        for (int sub = 0; sub < 8; ++sub)
#pragma unroll
            for (int cc = 0; cc < 4; ++cc) acc[sub][cc] = 0.f;

        const float4* smem4 = (const float4*)smem;
#pragma unroll
        for (int g = 0; g < 7; ++g) {
            float4 p[8];
#pragma unroll
            for (int sub = 0; sub < 8; ++sub)
                p[sub] = smem4[(sub * 48 + w) * 7 + g];   // bcast across cq
#pragma unroll
            for (int j = 0; j < 4; ++j) {
                int n = g * 4 + j;
                if (n < 27) {
                    int r = n / 3;              // dzdy (compile-time)
                    int dx = n - r * 3;
                    int col = r * 50 + w + dx;  // px = w+dx (clamped at stage)
                    f16x4 xr = *(const f16x4*)(X + col * 40 + cq * 4);
                    float4 xv = make_float4((float)xr.x, (float)xr.y,
                                            (float)xr.z, (float)xr.w);
#pragma unroll
                    for (int sub = 0; sub < 8; ++sub) {
                        float pv = comp4(p[sub], j);
                        acc[sub][0] = fmaf(xv.x, pv, acc[sub][0]);
                        acc[sub][1] = fmaf(xv.y, pv, acc[sub][1]);
                        acc[sub][2] = fmaf(xv.z, pv, acc[sub][2]);
                        acc[sub][3] = fmaf(xv.w, pv, acc[sub][3]);
                    }
                }
            }
        }

#pragma unroll
        for (int ij = 0; ij < 4; ++ij) {
            int i_ = ij >> 1, j_ = ij & 1;
            int rowz = 2 * d + i_;
            int rowy = 2 * hh + j_;
            int s0 = ij * 2;                    // sub for k=0
#pragma unroll
            for (int cc = 0; cc < 4; ++cc) {
                int c = cq * 4 + cc;
                float2 v;
                v.x = acc[s0][cc];              // k = 0
                v.y = acc[s0 + 1][cc];          // k = 1
                *(float2*)(out + (((size_t)c * 96 + rowz) * 96 + rowy) * 96 + 2 * w) = v;
            }
        }
    }
}

extern "C" void kernel_launch(void* const* d_in, const int* in_sizes, int n_in,
                              void* d_out, int out_size, void* d_ws, size_t ws_size,
                              hipStream_t stream) {
    const float* x    = (const float*)d_in[0];
    const float* feat = (const float*)d_in[1];
    const float* w1   = (const float*)d_in[2];
    const float* b1   = (const float*)d_in[3];
    const float* w2   = (const float*)d_in[4];
    const float* b2   = (const float*)d_in[5];
    float* out = (float*)d_out;

    _Float16* w1h   = (_Float16*)d_ws;                       //    110,592 B
    _Float16* w2h   = (_Float16*)((char*)d_ws + 110592);     //     28,672 B
    _Float16* featT = (_Float16*)((char*)d_ws + 139264);     //  7,077,888 B
    _Float16* xT    = (_Float16*)((char*)d_ws + 7217152);    //  7,077,888 B

    k_prep<<<3728, 256, 0, stream>>>(feat, x, w1, w2, featT, xT, w1h, w2h);
    k_main<<<2304, 512, 0, stream>>>(featT, xT, w1h, b1, w2h, b2, out);
}

// Round 9
// 254.221 us; speedup vs baseline: 1.2151x; 1.1968x over previous
//
#include <hip/hip_runtime.h>
#include <math.h>

#define NVOX 110592   // 48*48*48

typedef _Float16 f16x8 __attribute__((ext_vector_type(8)));
typedef _Float16 f16x4 __attribute__((ext_vector_type(4)));
typedef _Float16 f16x2 __attribute__((ext_vector_type(2)));
typedef float    f32x4 __attribute__((ext_vector_type(4)));

__device__ __forceinline__ float comp4(const float4& v, int j) {
    return j == 0 ? v.x : (j == 1 ? v.y : (j == 2 ? v.z : v.w));
}

// XCD-aware bijective swizzle (8 XCDs; grid % 8 == 0). Neighbor (d,h) rows
// share 2/3 of their halo -> keep them on the same XCD's L2.
__device__ __forceinline__ int xcd_swizzle(int bx, int nwg) {
    int chunk = nwg >> 3;
    return (bx & 7) * chunk + (bx >> 3);
}

// ---------------------------------------------------------------------------
// K0: merged prep.
//  blocks [0,3456): transpose+cast feat/x [32 c][NVOX] f32 -> [NVOX][32 c] f16
//  blocks [3456,3728): weights
//   w1 [64][32][27] f32 -> w1h [64 oc][27 tap][32 ci] f16
//   w2 [216][64] f32    -> w2h [224 oc][64 ci] f16 (rows 216.. zero)
// ---------------------------------------------------------------------------
__global__ __launch_bounds__(256) void k_prep(
    const float* __restrict__ feat, const float* __restrict__ x,
    const float* __restrict__ w1, const float* __restrict__ w2,
    _Float16* __restrict__ featT, _Float16* __restrict__ xT,
    _Float16* __restrict__ w1h, _Float16* __restrict__ w2h)
{
    __shared__ _Float16 tile[64 * 36];
    int bx = blockIdx.x;
    int t = threadIdx.x;

    if (bx >= 3456) {                        // weight prep
        int e = (bx - 3456) * 256 + t;
        if (e < 64 * 32 * 27) {
            int oc = e / 864;
            int r = e - oc * 864;
            int ci = r / 27;
            int tap = r - ci * 27;
            w1h[oc * 864 + tap * 32 + ci] = (_Float16)w1[e];
        }
        int e2 = e - 55296;
        if (e2 >= 0 && e2 < 224 * 64) {
            int oc = e2 >> 6, k = e2 & 63;
            w2h[e2] = (oc < 216) ? (_Float16)w2[oc * 64 + k] : (_Float16)0.f;
        }
        return;
    }

    int which = bx >= 1728;
    int v0 = (which ? bx - 1728 : bx) * 64;
    const float* s = which ? x : feat;
    _Float16* dt = which ? xT : featT;

    for (int i = t; i < 1024; i += 256) {
        int c2 = i >> 6, dv = i & 63;
        f16x2 v;
        v.x = (_Float16)s[(2 * c2) * NVOX + v0 + dv];
        v.y = (_Float16)s[(2 * c2 + 1) * NVOX + v0 + dv];
        *(f16x2*)(tile + dv * 36 + c2 * 2) = v;
    }
    __syncthreads();
    for (int i = t; i < 512; i += 256) {
        int dv = i >> 3, ch = i & 7;
        f16x4 v = *(const f16x4*)(tile + dv * 36 + ch * 4);
        *(f16x4*)(dt + (v0 + dv) * 32 + ch * 4) = v;
    }
}

// ---------------------------------------------------------------------------
// K1: fully fused per (d,h) row of 48 voxels, 512 threads (8 waves).
// Phases A-E byte-identical to round-3 (130 us, FETCH 28.7 MB, WRITE 148 MB).
// Phase F: R8's mapping (thread owns (w,cq), full-line stores) but processed
// in TWO PASSES of 4 subs each -> live state ~40 VGPR (acc[4][4]+p[4]),
// eliminating the scratch spill that R8's acc[8][4]+p[8] (~85 VGPR vs the
// 64-VGPR allocation) caused: spill traffic to VRAM was the +92 MB FETCH /
// +165 MB WRITE amplification.
//  A: stage featT 3x3 halo -> X [450 col][40 f16]          (36 KB)
//  B: conv3x3x3 + SiLU via MFMA, 8 waves
//  C: bias+SiLU -> hl [48 px][72 f16] (aliases X)
//  D: conv1x1 (64->216) via MFMA -> mbuf [8 sub][48 vox][28 f32] (43 KB)
//  E: stage xT halo -> X ; softmax(27) in mbuf (384 thr)
//  F: 27-tap combine, 384 thr = (tx 16)x(cq 8)x(wgrp 3), 2 passes x 4 subs
// LDS 79,008 B -> 2 blocks/CU.
// ---------------------------------------------------------------------------
__global__ __launch_bounds__(512, 4) void k_main(
    const _Float16* __restrict__ featT, const _Float16* __restrict__ xT,
    const _Float16* __restrict__ w1h, const float* __restrict__ b1,
    const _Float16* __restrict__ w2h, const float* __restrict__ b2,
    float* __restrict__ out)
{
    __shared__ float smem[19752];              // 79,008 B
    float* mbuf = smem;                         // [8][48][28] f32
    _Float16* X  = (_Float16*)(smem + 10752);   // [450][40] f16 staging
    _Float16* hl = (_Float16*)(smem + 10752);   // [48][72] f16 (aliases X)

    int bx = xcd_swizzle(blockIdx.x, gridDim.x);
    int d = bx / 48, hh = bx - d * 48;
    int t = threadIdx.x;

    // ---- phase A: stage featT neighborhood (replicate-clamped)
    for (int i = t; i < 1800; i += 512) {
        int col = i >> 2, chunk = i & 3;        // col = dzdy*50 + px
        int dzdy = col / 50;
        int px = col - dzdy * 50;
        int dz = dzdy / 3, dy = dzdy - dz * 3;
        int zz = min(max(d + dz - 1, 0), 47);
        int yy = min(max(hh + dy - 1, 0), 47);
        int xx = min(max(px - 1, 0), 47);
        int vox = (zz * 48 + yy) * 48 + xx;
        *(f16x8*)(X + col * 40 + chunk * 8) =
            *(const f16x8*)(featT + vox * 32 + chunk * 8);
    }
    __syncthreads();

    int wid = t >> 6;                           // 0..7
    int lane = t & 63;
    int mcol = lane & 15;
    int q = lane >> 4;
    int ocs = wid & 3;                          // oc strip for conv1

    // ---- phase B: conv1 MFMA. waves 0-3: px blocks {0,2}; waves 4-7: {1}
    f32x4 c1a = {0.f, 0.f, 0.f, 0.f};
    f32x4 c1b = {0.f, 0.f, 0.f, 0.f};
    {
        const _Float16* wbase = w1h + (ocs * 16 + mcol) * 864 + q * 8;
#pragma unroll 3
        for (int dzdy = 0; dzdy < 9; ++dzdy) {
            const _Float16* brow = X + (dzdy * 50 + mcol) * 40 + q * 8;
            const _Float16* wrow = wbase + dzdy * 96;
#pragma unroll
            for (int dx = 0; dx < 3; ++dx) {
                f16x8 av = *(const f16x8*)(wrow + dx * 32);
                const _Float16* bb = brow + dx * 40;
                if (wid < 4) {
                    f16x8 b0 = *(const f16x8*)(bb);
                    f16x8 b2v = *(const f16x8*)(bb + 32 * 40);
                    c1a = __builtin_amdgcn_mfma_f32_16x16x32_f16(av, b0, c1a, 0, 0, 0);
                    c1b = __builtin_amdgcn_mfma_f32_16x16x32_f16(av, b2v, c1b, 0, 0, 0);
                } else {
                    f16x8 b1v = *(const f16x8*)(bb + 16 * 40);
                    c1a = __builtin_amdgcn_mfma_f32_16x16x32_f16(av, b1v, c1a, 0, 0, 0);
                }
            }
        }
    }
    __syncthreads();                            // all X reads done

    // ---- phase C: bias + SiLU -> hl (aliases X head)
    {
        float4 bv = ((const float4*)b1)[ocs * 4 + q];
        int pxb0 = (wid < 4) ? 0 : 1;
        int px0 = pxb0 * 16 + mcol;
        f16x4 o; float s;
        s = c1a[0] + bv.x; o.x = (_Float16)(s / (1.f + __expf(-s)));
        s = c1a[1] + bv.y; o.y = (_Float16)(s / (1.f + __expf(-s)));
        s = c1a[2] + bv.z; o.z = (_Float16)(s / (1.f + __expf(-s)));
        s = c1a[3] + bv.w; o.w = (_Float16)(s / (1.f + __expf(-s)));
        *(f16x4*)(hl + px0 * 72 + ocs * 16 + q * 4) = o;
        if (wid < 4) {
            int px1 = 32 + mcol;
            s = c1b[0] + bv.x; o.x = (_Float16)(s / (1.f + __expf(-s)));
            s = c1b[1] + bv.y; o.y = (_Float16)(s / (1.f + __expf(-s)));
            s = c1b[2] + bv.z; o.z = (_Float16)(s / (1.f + __expf(-s)));
            s = c1b[3] + bv.w; o.w = (_Float16)(s / (1.f + __expf(-s)));
            *(f16x4*)(hl + px1 * 72 + ocs * 16 + q * 4) = o;
        }
    }
    __syncthreads();                            // hl complete

    // ---- phase D: conv2 MFMA, 42 tiles (14 mt x 3 nt) over 8 waves
    for (int tt = wid; tt < 42; tt += 8) {
        int mt = tt / 3, nt = tt - mt * 3;
        float bias[4];
#pragma unroll
        for (int rr = 0; rr < 4; ++rr) {
            int oc = mt * 16 + q * 4 + rr;
            bias[rr] = (oc < 216) ? b2[oc] : 0.f;
        }
        f32x4 acc = {bias[0], bias[1], bias[2], bias[3]};
#pragma unroll
        for (int ks = 0; ks < 2; ++ks) {
            f16x8 av = *(const f16x8*)(w2h + (mt * 16 + mcol) * 64 + ks * 32 + q * 8);
            f16x8 bv = *(const f16x8*)(hl + (nt * 16 + mcol) * 72 + ks * 32 + q * 8);
            acc = __builtin_amdgcn_mfma_f32_16x16x32_f16(av, bv, acc, 0, 0, 0);
        }
        int vox = nt * 16 + mcol;
#pragma unroll
        for (int rr = 0; rr < 4; ++rr) {
            int oc = mt * 16 + q * 4 + rr;
            if (oc < 216) {
                int sub = oc / 27;
                int n = oc - sub * 27;
                mbuf[(sub * 48 + vox) * 28 + n] = acc[rr];
            }
        }
    }
    __syncthreads();                            // mbuf complete, hl dead

    // ---- phase E: stage xT halo into X (overwrites hl) + softmax in mbuf
    for (int i = t; i < 1800; i += 512) {
        int col = i >> 2, chunk = i & 3;
        int dzdy = col / 50;
        int px = col - dzdy * 50;
        int dz = dzdy / 3, dy = dzdy - dz * 3;
        int zz = min(max(d + dz - 1, 0), 47);
        int yy = min(max(hh + dy - 1, 0), 47);
        int xx = min(max(px - 1, 0), 47);
        int vox = (zz * 48 + yy) * 48 + xx;
        *(f16x8*)(X + col * 40 + chunk * 8) =
            *(const f16x8*)(xT + vox * 32 + chunk * 8);
    }
    if (t < 384) {                              // 8 sub x 48 vox rows
        int sub = t / 48;
        int vox = t - sub * 48;
        float4* p4p = (float4*)(mbuf + (sub * 48 + vox) * 28);
        float4 v[7];
#pragma unroll
        for (int g = 0; g < 7; ++g) v[g] = p4p[g];
        float mx = fmaxf(fmaxf(v[6].x, v[6].y), v[6].z);
#pragma unroll
        for (int g = 0; g < 6; ++g)
            mx = fmaxf(mx, fmaxf(fmaxf(v[g].x, v[g].y), fmaxf(v[g].z, v[g].w)));
        float s = 0.f;
#pragma unroll
        for (int g = 0; g < 7; ++g) {
            v[g].x = __expf(v[g].x - mx);
            v[g].y = __expf(v[g].y - mx);
            v[g].z = __expf(v[g].z - mx);
            v[g].w = __expf(v[g].w - mx);
        }
        v[6].w = 0.f;                           // tap 27 pad
#pragma unroll
        for (int g = 0; g < 7; ++g) s += v[g].x + v[g].y + v[g].z + v[g].w;
        float inv = 1.f / s;
#pragma unroll
        for (int g = 0; g < 7; ++g) {
            v[g].x *= inv; v[g].y *= inv; v[g].z *= inv; v[g].w *= inv;
            p4p[g] = v[g];
        }
    }
    __syncthreads();

    // ---- phase F: 384 thr = (tx 16) x (cq 8) x (wgrp 3); w = wgrp*16+tx.
    // TWO PASSES of 4 subs: live regs per pass = acc[4][4] + p[4] (~40 VGPR,
    // no spill).  16 lanes span 16 consecutive w -> full 128B line stores.
    // out[c][2d+i][2h+j][2w+k] = sum_n p[(i*2+j)*2+k][w][n] * x[c][nb(w,n)]
    if (t < 384) {
        int tx = t & 15;
        int cq = (t >> 4) & 7;
        int wgrp = t >> 7;                      // 0..2
        int w = wgrp * 16 + tx;
        const float4* smem4 = (const float4*)smem;

#pragma unroll
        for (int pass = 0; pass < 2; ++pass) {
            float acc[4][4];
#pragma unroll
            for (int sp = 0; sp < 4; ++sp)
#pragma unroll
                for (int cc = 0; cc < 4; ++cc) acc[sp][cc] = 0.f;

#pragma unroll
            for (int g = 0; g < 7; ++g) {
                float4 p[4];
#pragma unroll
                for (int sp = 0; sp < 4; ++sp)
                    p[sp] = smem4[((pass * 4 + sp) * 48 + w) * 7 + g];
#pragma unroll
                for (int j = 0; j < 4; ++j) {
                    int n = g * 4 + j;
                    if (n < 27) {
                        int r = n / 3;          // dzdy (compile-time)
                        int dx = n - r * 3;
                        int col = r * 50 + w + dx;   // px clamped at stage
                        f16x4 xr = *(const f16x4*)(X + col * 40 + cq * 4);
                        float4 xv = make_float4((float)xr.x, (float)xr.y,
                                                (float)xr.z, (float)xr.w);
#pragma unroll
                        for (int sp = 0; sp < 4; ++sp) {
                            float pv = comp4(p[sp], j);
                            acc[sp][0] = fmaf(xv.x, pv, acc[sp][0]);
                            acc[sp][1] = fmaf(xv.y, pv, acc[sp][1]);
                            acc[sp][2] = fmaf(xv.z, pv, acc[sp][2]);
                            acc[sp][3] = fmaf(xv.w, pv, acc[sp][3]);
                        }
                    }
                }
            }

            // stores for subs [pass*4, pass*4+4): ij = pass*2 + {0,1}
#pragma unroll
            for (int ijh = 0; ijh < 2; ++ijh) {
                int ij = pass * 2 + ijh;
                int i_ = ij >> 1, j_ = ij & 1;
                int rowz = 2 * d + i_;
                int rowy = 2 * hh + j_;
#pragma unroll
                for (int cc = 0; cc < 4; ++cc) {
                    int c = cq * 4 + cc;
                    float2 v;
                    v.x = acc[ijh * 2][cc];     // k = 0
                    v.y = acc[ijh * 2 + 1][cc]; // k = 1
                    *(float2*)(out + (((size_t)c * 96 + rowz) * 96 + rowy) * 96 + 2 * w) = v;
                }
            }
        }
    }
}

extern "C" void kernel_launch(void* const* d_in, const int* in_sizes, int n_in,
                              void* d_out, int out_size, void* d_ws, size_t ws_size,
                              hipStream_t stream) {
    const float* x    = (const float*)d_in[0];
    const float* feat = (const float*)d_in[1];
    const float* w1   = (const float*)d_in[2];
    const float* b1   = (const float*)d_in[3];
    const float* w2   = (const float*)d_in[4];
    const float* b2   = (const float*)d_in[5];
    float* out = (float*)d_out;

    _Float16* w1h   = (_Float16*)d_ws;                       //    110,592 B
    _Float16* w2h   = (_Float16*)((char*)d_ws + 110592);     //     28,672 B
    _Float16* featT = (_Float16*)((char*)d_ws + 139264);     //  7,077,888 B
    _Float16* xT    = (_Float16*)((char*)d_ws + 7217152);    //  7,077,888 B

    k_prep<<<3728, 256, 0, stream>>>(feat, x, w1, w2, featT, xT, w1h, w2h);
    k_main<<<2304, 512, 0, stream>>>(featT, xT, w1h, b1, w2h, b2, out);
}

// Round 10
// 249.372 us; speedup vs baseline: 1.2387x; 1.0194x over previous
//
#include <hip/hip_runtime.h>
#include <math.h>

#define NVOX 110592   // 48*48*48

typedef _Float16 f16x8 __attribute__((ext_vector_type(8)));
typedef _Float16 f16x4 __attribute__((ext_vector_type(4)));
typedef _Float16 f16x2 __attribute__((ext_vector_type(2)));
typedef float    f32x4 __attribute__((ext_vector_type(4)));

__device__ __forceinline__ void fmas4(float4& a, const float4& xv, float p) {
    a.x = fmaf(xv.x, p, a.x);
    a.y = fmaf(xv.y, p, a.y);
    a.z = fmaf(xv.z, p, a.z);
    a.w = fmaf(xv.w, p, a.w);
}
__device__ __forceinline__ float comp4(const float4& v, int j) {
    return j == 0 ? v.x : (j == 1 ? v.y : (j == 2 ? v.z : v.w));
}

// XCD-aware bijective swizzle (8 XCDs; grid % 8 == 0). Neighbor (d,h) rows
// share 2/3 of their halo -> keep them on the same XCD's L2.
__device__ __forceinline__ int xcd_swizzle(int bx, int nwg) {
    int chunk = nwg >> 3;
    return (bx & 7) * chunk + (bx >> 3);
}

// ---------------------------------------------------------------------------
// K0: merged prep.
//  blocks [0,3456): transpose+cast feat/x [32 c][NVOX] f32 -> [NVOX][32 c] f16
//  blocks [3456,3728): weights
//   w1 [64][32][27] f32 -> w1h [64 oc][27 tap][32 ci] f16
//   w2 [216][64] f32    -> w2h [224 oc][64 ci] f16 (rows 216.. zero)
// ---------------------------------------------------------------------------
__global__ __launch_bounds__(256) void k_prep(
    const float* __restrict__ feat, const float* __restrict__ x,
    const float* __restrict__ w1, const float* __restrict__ w2,
    _Float16* __restrict__ featT, _Float16* __restrict__ xT,
    _Float16* __restrict__ w1h, _Float16* __restrict__ w2h)
{
    __shared__ _Float16 tile[64 * 36];
    int bx = blockIdx.x;
    int t = threadIdx.x;

    if (bx >= 3456) {                        // weight prep
        int e = (bx - 3456) * 256 + t;
        if (e < 64 * 32 * 27) {
            int oc = e / 864;
            int r = e - oc * 864;
            int ci = r / 27;
            int tap = r - ci * 27;
            w1h[oc * 864 + tap * 32 + ci] = (_Float16)w1[e];
        }
        int e2 = e - 55296;
        if (e2 >= 0 && e2 < 224 * 64) {
            int oc = e2 >> 6, k = e2 & 63;
            w2h[e2] = (oc < 216) ? (_Float16)w2[oc * 64 + k] : (_Float16)0.f;
        }
        return;
    }

    int which = bx >= 1728;
    int v0 = (which ? bx - 1728 : bx) * 64;
    const float* s = which ? x : feat;
    _Float16* dt = which ? xT : featT;

    for (int i = t; i < 1024; i += 256) {
        int c2 = i >> 6, dv = i & 63;
        f16x2 v;
        v.x = (_Float16)s[(2 * c2) * NVOX + v0 + dv];
        v.y = (_Float16)s[(2 * c2 + 1) * NVOX + v0 + dv];
        *(f16x2*)(tile + dv * 36 + c2 * 2) = v;
    }
    __syncthreads();
    for (int i = t; i < 512; i += 256) {
        int dv = i >> 3, ch = i & 7;
        f16x4 v = *(const f16x4*)(tile + dv * 36 + ch * 4);
        *(f16x4*)(dt + (v0 + dv) * 32 + ch * 4) = v;
    }
}

// ---------------------------------------------------------------------------
// K1: fully fused per (d,h) row of 48 voxels, 512 threads (8 waves).
// = Round-3 kernel (130 us, FETCH 28.7 MB, WRITE 148 MB) with ONE change:
// phases B/C use the 6-wave structure (wave = pxb x och) so each X column
// is ds_read ONCE for 2 MFMAs instead of once per oc-strip (4x) -> LDS-pipe
// reads in B drop 432 -> 162 wave-b128 per block.  Phase F is R3's verbatim
// (the only F variant that avoids the FETCH/WRITE amplification attractor).
//  A: stage featT 3x3 halo -> X [450 col][40 f16]          (36 KB)
//  B: conv3x3x3 via MFMA, 6 waves x (px-block, oc-half)
//  C: bias+SiLU -> hl [48 px][72 f16] (aliases X)
//  D: conv1x1 (64->216) via MFMA -> mbuf [8 sub][48 vox][28 f32] (43 KB)
//  E: stage xT halo -> X (overwrites hl) ; softmax(27) in mbuf (384 thr)
//  F: 27-tap combine, 512 thr (R3 mapping: tx8 x cq8 x sp4 x half2)
// LDS 79,008 B -> 2 blocks/CU.
// ---------------------------------------------------------------------------
__global__ __launch_bounds__(512, 4) void k_main(
    const _Float16* __restrict__ featT, const _Float16* __restrict__ xT,
    const _Float16* __restrict__ w1h, const float* __restrict__ b1,
    const _Float16* __restrict__ w2h, const float* __restrict__ b2,
    float* __restrict__ out)
{
    __shared__ float smem[19752];              // 79,008 B
    float* mbuf = smem;                         // [8][48][28] f32
    _Float16* X  = (_Float16*)(smem + 10752);   // [450][40] f16 staging
    _Float16* hl = (_Float16*)(smem + 10752);   // [48][72] f16 (aliases X)

    int bx = xcd_swizzle(blockIdx.x, gridDim.x);
    int d = bx / 48, hh = bx - d * 48;
    int t = threadIdx.x;

    // ---- phase A: stage featT neighborhood (replicate-clamped)
    for (int i = t; i < 1800; i += 512) {
        int col = i >> 2, chunk = i & 3;        // col = dzdy*50 + px
        int dzdy = col / 50;
        int px = col - dzdy * 50;
        int dz = dzdy / 3, dy = dzdy - dz * 3;
        int zz = min(max(d + dz - 1, 0), 47);
        int yy = min(max(hh + dy - 1, 0), 47);
        int xx = min(max(px - 1, 0), 47);
        int vox = (zz * 48 + yy) * 48 + xx;
        *(f16x8*)(X + col * 40 + chunk * 8) =
            *(const f16x8*)(featT + vox * 32 + chunk * 8);
    }
    __syncthreads();

    int wid = t >> 6;                           // 0..7
    int lane = t & 63;
    int mcol = lane & 15;
    int q = lane >> 4;

    // ---- phase B: conv1 MFMA. 6 waves: wave = (px-block 0..2) x (oc-half)
    f32x4 c1a = {0.f, 0.f, 0.f, 0.f};
    f32x4 c1b = {0.f, 0.f, 0.f, 0.f};
    int pxb = wid >> 1;                         // 0..2 (waves 6,7 idle)
    int och = wid & 1;
    if (wid < 6) {
        const _Float16* wb0 = w1h + (och * 32 + mcol) * 864 + q * 8;
        const _Float16* wb1 = wb0 + 16 * 864;
#pragma unroll 3
        for (int dzdy = 0; dzdy < 9; ++dzdy) {
            const _Float16* brow = X + (dzdy * 50 + pxb * 16 + mcol) * 40 + q * 8;
            const _Float16* wr0 = wb0 + dzdy * 96;
            const _Float16* wr1 = wb1 + dzdy * 96;
#pragma unroll
            for (int dx = 0; dx < 3; ++dx) {
                f16x8 bv = *(const f16x8*)(brow + dx * 40);
                f16x8 a0 = *(const f16x8*)(wr0 + dx * 32);
                f16x8 a1 = *(const f16x8*)(wr1 + dx * 32);
                c1a = __builtin_amdgcn_mfma_f32_16x16x32_f16(a0, bv, c1a, 0, 0, 0);
                c1b = __builtin_amdgcn_mfma_f32_16x16x32_f16(a1, bv, c1b, 0, 0, 0);
            }
        }
    }
    __syncthreads();                            // all X reads done

    // ---- phase C: bias + SiLU -> hl (aliases X head)
    if (wid < 6) {
        int pxv = pxb * 16 + mcol;              // D: col = lane&15
        float4 bva = ((const float4*)b1)[(och * 2) * 4 + q];
        float4 bvb = ((const float4*)b1)[(och * 2 + 1) * 4 + q];
        f16x4 o; float s;
        s = c1a[0] + bva.x; o.x = (_Float16)(s / (1.f + __expf(-s)));
        s = c1a[1] + bva.y; o.y = (_Float16)(s / (1.f + __expf(-s)));
        s = c1a[2] + bva.z; o.z = (_Float16)(s / (1.f + __expf(-s)));
        s = c1a[3] + bva.w; o.w = (_Float16)(s / (1.f + __expf(-s)));
        *(f16x4*)(hl + pxv * 72 + och * 32 + q * 4) = o;
        s = c1b[0] + bvb.x; o.x = (_Float16)(s / (1.f + __expf(-s)));
        s = c1b[1] + bvb.y; o.y = (_Float16)(s / (1.f + __expf(-s)));
        s = c1b[2] + bvb.z; o.z = (_Float16)(s / (1.f + __expf(-s)));
        s = c1b[3] + bvb.w; o.w = (_Float16)(s / (1.f + __expf(-s)));
        *(f16x4*)(hl + pxv * 72 + och * 32 + 16 + q * 4) = o;
    }
    __syncthreads();                            // hl complete

    // ---- phase D: conv2 MFMA, 42 tiles (14 mt x 3 nt) over 8 waves
    for (int tt = wid; tt < 42; tt += 8) {
        int mt = tt / 3, nt = tt - mt * 3;
        float bias[4];
#pragma unroll
        for (int rr = 0; rr < 4; ++rr) {
            int oc = mt * 16 + q * 4 + rr;
            bias[rr] = (oc < 216) ? b2[oc] : 0.f;
        }
        f32x4 acc = {bias[0], bias[1], bias[2], bias[3]};
#pragma unroll
        for (int ks = 0; ks < 2; ++ks) {
            f16x8 av = *(const f16x8*)(w2h + (mt * 16 + mcol) * 64 + ks * 32 + q * 8);
            f16x8 bv = *(const f16x8*)(hl + (nt * 16 + mcol) * 72 + ks * 32 + q * 8);
            acc = __builtin_amdgcn_mfma_f32_16x16x32_f16(av, bv, acc, 0, 0, 0);
        }
        int vox = nt * 16 + mcol;
#pragma unroll
        for (int rr = 0; rr < 4; ++rr) {
            int oc = mt * 16 + q * 4 + rr;
            if (oc < 216) {
                int sub = oc / 27;
                int n = oc - sub * 27;
                mbuf[(sub * 48 + vox) * 28 + n] = acc[rr];
            }
        }
    }
    __syncthreads();                            // mbuf complete, hl dead

    // ---- phase E: stage xT halo into X (overwrites hl) + softmax in mbuf
    for (int i = t; i < 1800; i += 512) {
        int col = i >> 2, chunk = i & 3;
        int dzdy = col / 50;
        int px = col - dzdy * 50;
        int dz = dzdy / 3, dy = dzdy - dz * 3;
        int zz = min(max(d + dz - 1, 0), 47);
        int yy = min(max(hh + dy - 1, 0), 47);
        int xx = min(max(px - 1, 0), 47);
        int vox = (zz * 48 + yy) * 48 + xx;
        *(f16x8*)(X + col * 40 + chunk * 8) =
            *(const f16x8*)(xT + vox * 32 + chunk * 8);
    }
    if (t < 384) {                              // 8 sub x 48 vox rows
        int sub = t / 48;
        int vox = t - sub * 48;
        float4* p4p = (float4*)(mbuf + (sub * 48 + vox) * 28);
        float4 v[7];
#pragma unroll
        for (int g = 0; g < 7; ++g) v[g] = p4p[g];
        float mx = fmaxf(fmaxf(v[6].x, v[6].y), v[6].z);
#pragma unroll
        for (int g = 0; g < 6; ++g)
            mx = fmaxf(mx, fmaxf(fmaxf(v[g].x, v[g].y), fmaxf(v[g].z, v[g].w)));
        float s = 0.f;
#pragma unroll
        for (int g = 0; g < 7; ++g) {
            v[g].x = __expf(v[g].x - mx);
            v[g].y = __expf(v[g].y - mx);
            v[g].z = __expf(v[g].z - mx);
            v[g].w = __expf(v[g].w - mx);
        }
        v[6].w = 0.f;                           // tap 27 pad
#pragma unroll
        for (int g = 0; g < 7; ++g) s += v[g].x + v[g].y + v[g].z + v[g].w;
        float inv = 1.f / s;
#pragma unroll
        for (int g = 0; g < 7; ++g) {
            v[g].x *= inv; v[g].y *= inv; v[g].z *= inv; v[g].w *= inv;
            p4p[g] = v[g];
        }
    }
    __syncthreads();

    // ---- phase F (R3 verbatim): 512 thr; u=t&255, half=t>>8, w0=half*24;
    // tx = u&7, cq = (u>>3)&7, sp = u>>6.
    // out[c][2d+i][2h+j][2w+k] = sum_n p[sub][w][n]*x[c][nb(w,n)]
    {
        float4* smem4 = (float4*)smem;
        int u = t & 255;
        int half = t >> 8;
        int w0 = half * 24;
        int tx = u & 7, ty = u >> 3;
        int cq = ty & 7, sp = ty >> 3;          // sp -> (i,j)
        float4 acc[2][3];
#pragma unroll
        for (int s = 0; s < 2; ++s)
#pragma unroll
            for (int wi = 0; wi < 3; ++wi)
                acc[s][wi] = make_float4(0.f, 0.f, 0.f, 0.f);

#pragma unroll
        for (int g = 0; g < 7; ++g) {
            float4 p4[2][3];
#pragma unroll
            for (int s = 0; s < 2; ++s)
#pragma unroll
                for (int wi = 0; wi < 3; ++wi)
                    p4[s][wi] = smem4[((sp * 2 + s) * 48 + w0 + tx + wi * 8) * 7 + g];
#pragma unroll
            for (int j = 0; j < 4; ++j) {
                int n = g * 4 + j;
                if (n < 27) {
                    int dz = n / 9;
                    int rem = n - dz * 9;
                    int dy = rem / 3, dx = rem - dy * 3;
#pragma unroll
                    for (int wi = 0; wi < 3; ++wi) {
                        int col = (dz * 3 + dy) * 50 + w0 + tx + wi * 8 + dx;
                        f16x4 xr = *(const f16x4*)(X + col * 40 + cq * 4);
                        float4 xv = make_float4((float)xr.x, (float)xr.y,
                                                (float)xr.z, (float)xr.w);
                        fmas4(acc[0][wi], xv, comp4(p4[0][wi], j));
                        fmas4(acc[1][wi], xv, comp4(p4[1][wi], j));
                    }
                }
            }
        }

        int i_ = sp >> 1, j_ = sp & 1;
        int rowz = 2 * d + i_;
        int rowy = 2 * hh + j_;
#pragma unroll
        for (int wi = 0; wi < 3; ++wi) {
            int wg = w0 + tx + wi * 8;
#pragma unroll
            for (int cc = 0; cc < 4; ++cc) {
                int c = cq * 4 + cc;
                float2 v;
                v.x = comp4(acc[0][wi], cc);    // k = 0
                v.y = comp4(acc[1][wi], cc);    // k = 1
                *(float2*)(out + (((size_t)c * 96 + rowz) * 96 + rowy) * 96 + 2 * wg) = v;
            }
        }
    }
}

extern "C" void kernel_launch(void* const* d_in, const int* in_sizes, int n_in,
                              void* d_out, int out_size, void* d_ws, size_t ws_size,
                              hipStream_t stream) {
    const float* x    = (const float*)d_in[0];
    const float* feat = (const float*)d_in[1];
    const float* w1   = (const float*)d_in[2];
    const float* b1   = (const float*)d_in[3];
    const float* w2   = (const float*)d_in[4];
    const float* b2   = (const float*)d_in[5];
    float* out = (float*)d_out;

    _Float16* w1h   = (_Float16*)d_ws;                       //    110,592 B
    _Float16* w2h   = (_Float16*)((char*)d_ws + 110592);     //     28,672 B
    _Float16* featT = (_Float16*)((char*)d_ws + 139264);     //  7,077,888 B
    _Float16* xT    = (_Float16*)((char*)d_ws + 7217152);    //  7,077,888 B

    k_prep<<<3728, 256, 0, stream>>>(feat, x, w1, w2, featT, xT, w1h, w2h);
    k_main<<<2304, 512, 0, stream>>>(featT, xT, w1h, b1, w2h, b2, out);
}